// Round 5
// baseline (995.533 us; speedup 1.0000x reference)
//
#include <hip/hip_runtime.h>
#include <stdint.h>

#define N_ROWS 131072
#define D_IN   512
#define D_OUT  512
#define BM     32
#define TPB    8                          // row-tiles per persistent block
#define THREADS 512
#define GRID   (N_ROWS / (BM * TPB))      // 512 blocks = exactly 2 per CU
#define LDA    520                        // padded bf16 row stride (bank-uniform b128 reads)
#define ABUF   (BM * LDA)                 // 16640 elems per A buffer
#define LDS_BYTES (2 * ABUF * 2)          // 66560 B -> 2 blocks/CU

typedef short  s8v __attribute__((ext_vector_type(8)));   // 8 bf16 bits (4 VGPRs)
typedef float  f4v __attribute__((ext_vector_type(4)));   // MFMA acc
typedef unsigned int u32;

// fp32 -> bf16 bits, round-to-nearest-even (exact for 0.0/1.0 spike inputs)
__device__ __forceinline__ unsigned short f2bf(float f) {
    u32 b = __builtin_bit_cast(u32, f);
    b += 0x7FFFu + ((b >> 16) & 1u);
    return (unsigned short)(b >> 16);
}

// ---------------------------------------------------------------------------
// W fp32 [k][n] -> Wb bf16, k-tiled transpose: Wb[(kt*512 + n)*32 + kk] =
// bf16(W[(kt*32 + kk)*512 + n]).  A GEMM B-fragment read (n = base+c over 16
// lanes, kk = q*8..q*8+7) is then 64 lanes x 16 B FULLY CONTIGUOUS = one
// perfectly-coalesced 1 KB L2 transaction.  (Verified correct in R2/R4.)
// ---------------------------------------------------------------------------
__global__ void convert_w(const float* __restrict__ W, unsigned short* __restrict__ wb) {
    int t  = blockIdx.x * blockDim.x + threadIdx.x;   // 0 .. 262143
    int kk = t & 31;
    int n  = (t >> 5) & 511;
    int kt = t >> 14;
    wb[t] = f2bf(W[(kt * 32 + kk) * 512 + n]);
}

// ---------------------------------------------------------------------------
// Persistent pipelined GEMM: each block owns 8 consecutive 32-row tiles.
// Per tile: [lgkm barrier] [issue X loads t+1] [compute: B direct-from-L2]
//           [convert+ds_write A(t+1)] [store Y(t)].
// X loads and Y stores are reg-destined vmem ops that FLY ACROSS the raw
// s_barrier (only lgkmcnt is drained) -> HBM stream stays continuously busy
// instead of idling during compute/store phases.  One barrier per tile.
// ---------------------------------------------------------------------------
__global__ __launch_bounds__(THREADS, 4) void sparse_dense_gemm(
    const float* __restrict__ X, const unsigned short* __restrict__ Wb,
    const float* __restrict__ bias, float* __restrict__ Y)
{
    extern __shared__ char smem[];
    unsigned short* Ash = (unsigned short*)smem;     // [2][32][520] bf16

    const int tid  = threadIdx.x;
    const int lane = tid & 63;
    const int wv   = tid >> 6;          // 0..7 -> cols [wv*64, wv*64+64)
    const int c    = lane & 15;         // frag row/col selector
    const int q    = lane >> 4;         // quad 0..3 -> k-slot q*8..q*8+7

    // X staging map: 512 thr x 8 float4 = 64 KB tile; row = i*4 + (tid>>7)
    const int xrow  = tid >> 7;          // 0..3
    const int xcolb = (tid & 127) * 4;   // f32 col base (uint2 LDS write, 2 lanes/bank = free)

    const unsigned short* Bp = Wb + (wv * 64 + c) * 32 + q * 8;
    const size_t tile0 = (size_t)blockIdx.x * TPB;

    // bias is per-thread-constant across tiles: hoist
    float bv[4];
    #pragma unroll
    for (int nf = 0; nf < 4; ++nf) bv[nf] = bias[wv * 64 + nf * 16 + c];

    // ---- prologue: stage tile 0 into buffer 0 ----
    {
        const float4* Xb = (const float4*)(X + tile0 * BM * D_IN);
        float4 v[8];
        #pragma unroll
        for (int i = 0; i < 8; ++i) v[i] = Xb[i * 512 + tid];
        #pragma unroll
        for (int i = 0; i < 8; ++i) {
            u32 lo = (u32)f2bf(v[i].x) | ((u32)f2bf(v[i].y) << 16);
            u32 hi = (u32)f2bf(v[i].z) | ((u32)f2bf(v[i].w) << 16);
            *(uint2*)(Ash + (i * 4 + xrow) * LDA + xcolb) = make_uint2(lo, hi);
        }
    }

    #pragma unroll 2
    for (int t = 0; t < TPB; ++t) {
        // raw barrier: drain LDS ops only; reg-destined vmem crosses freely
        asm volatile("s_waitcnt lgkmcnt(0)" ::: "memory");
        __builtin_amdgcn_s_barrier();

        const int p = t & 1;
        const unsigned short* Ap = Ash + p * ABUF + c * LDA + q * 8;

        // B prologue: k-steps 0 and 1 in flight (L2-resident, 1 KB coalesced)
        s8v b0[4], b1[4];
        #pragma unroll
        for (int nf = 0; nf < 4; ++nf) b0[nf] = *(const s8v*)(Bp + nf * 512);
        #pragma unroll
        for (int nf = 0; nf < 4; ++nf) b1[nf] = *(const s8v*)(Bp + 16384 + nf * 512);

        // issue next-tile X loads now -> they land during the 16-step compute
        float4 xv[8];
        const bool hasNext = (t + 1 < TPB);
        if (hasNext) {
            const float4* Xn = (const float4*)(X + (tile0 + t + 1) * BM * D_IN);
            #pragma unroll
            for (int i = 0; i < 8; ++i) xv[i] = Xn[i * 512 + tid];
        }

        f4v acc[2][4];
        #pragma unroll
        for (int mf = 0; mf < 2; ++mf)
            #pragma unroll
            for (int nf = 0; nf < 4; ++nf)
                acc[mf][nf] = f4v{0.f, 0.f, 0.f, 0.f};

        // 16 k-steps, depth-2 B ping-pong (verified R4 mapping)
        #pragma unroll
        for (int it2 = 0; it2 < 8; ++it2) {
            const int itE = 2 * it2, itO = itE + 1;
            #pragma unroll
            for (int mf = 0; mf < 2; ++mf) {
                s8v af = *(const s8v*)(Ap + (mf * 16) * LDA + itE * 32);
                #pragma unroll
                for (int nf = 0; nf < 4; ++nf)
                    acc[mf][nf] = __builtin_amdgcn_mfma_f32_16x16x32_bf16(
                        af, b0[nf], acc[mf][nf], 0, 0, 0);
            }
            if (itE + 2 < 16) {
                #pragma unroll
                for (int nf = 0; nf < 4; ++nf)
                    b0[nf] = *(const s8v*)(Bp + (itE + 2) * 16384 + nf * 512);
            }
            #pragma unroll
            for (int mf = 0; mf < 2; ++mf) {
                s8v af = *(const s8v*)(Ap + (mf * 16) * LDA + itO * 32);
                #pragma unroll
                for (int nf = 0; nf < 4; ++nf)
                    acc[mf][nf] = __builtin_amdgcn_mfma_f32_16x16x32_bf16(
                        af, b1[nf], acc[mf][nf], 0, 0, 0);
            }
            if (itO + 2 < 16) {
                #pragma unroll
                for (int nf = 0; nf < 4; ++nf)
                    b1[nf] = *(const s8v*)(Bp + (itO + 2) * 16384 + nf * 512);
            }
        }

        // convert + ds_write next tile (X latency already paid under compute)
        if (hasNext) {
            unsigned short* An = Ash + (p ^ 1) * ABUF;
            #pragma unroll
            for (int i = 0; i < 8; ++i) {
                u32 lo = (u32)f2bf(xv[i].x) | ((u32)f2bf(xv[i].y) << 16);
                u32 hi = (u32)f2bf(xv[i].z) | ((u32)f2bf(xv[i].w) << 16);
                *(uint2*)(An + (i * 4 + xrow) * LDA + xcolb) = make_uint2(lo, hi);
            }
        }

        // store Y(t): C/D layout col=lane&15, row=(lane>>4)*4+i (verified)
        const size_t r0 = (tile0 + t) * BM;
        #pragma unroll
        for (int nf = 0; nf < 4; ++nf) {
            const int col = wv * 64 + nf * 16 + c;
            #pragma unroll
            for (int mf = 0; mf < 2; ++mf) {
                #pragma unroll
                for (int i = 0; i < 4; ++i) {
                    size_t row = r0 + mf * 16 + q * 4 + i;
                    Y[row * D_OUT + col] = acc[mf][nf][i] + bv[nf];
                }
            }
        }
    }
}

extern "C" void kernel_launch(void* const* d_in, const int* in_sizes, int n_in,
                              void* d_out, int out_size, void* d_ws, size_t ws_size,
                              hipStream_t stream) {
    const float* X    = (const float*)d_in[0];
    const float* W    = (const float*)d_in[1];
    const float* bias = (const float*)d_in[2];
    float* Y          = (float*)d_out;
    unsigned short* wsb = (unsigned short*)d_ws;   // 512 KB bf16 k-tiled W^T copy

    (void)hipFuncSetAttribute((const void*)sparse_dense_gemm,
                              hipFuncAttributeMaxDynamicSharedMemorySize, LDS_BYTES);

    convert_w<<<1024, 256, 0, stream>>>(W, wsb);
    sparse_dense_gemm<<<GRID, THREADS, LDS_BYTES, stream>>>(X, wsb, bias, Y);
}

// Round 6
// 467.589 us; speedup vs baseline: 2.1291x; 2.1291x over previous
//
#include <hip/hip_runtime.h>
#include <stdint.h>

#define N_ROWS 131072
#define D_IN   512
#define D_OUT  512
#define BM     64
#define BK     32
#define NKT    (D_IN / BK)            // 16
#define THREADS 512

// LDS: B dbuf 2 x [512][32] bf16 = 64 KB, A dbuf 2 x [64][32] bf16 = 8 KB
// total 73728 B -> 2 blocks/CU.  Epilogue reuses the 64 KB B region for
// full-line Y staging.
#define BTILE  (D_OUT * BK)           // 16384 elems
#define ATILE  (BM * BK)              // 2048 elems
#define LDS_BYTES ((2 * BTILE + 2 * ATILE) * 2)

typedef short  s8v __attribute__((ext_vector_type(8)));   // 8 bf16 bits (4 VGPRs)
typedef float  f4v __attribute__((ext_vector_type(4)));   // MFMA acc
typedef unsigned int u32;

// fp32 -> bf16 bits, round-to-nearest-even (exact for 0.0/1.0 spike inputs)
__device__ __forceinline__ unsigned short f2bf(float f) {
    u32 b = __builtin_bit_cast(u32, f);
    b += 0x7FFFu + ((b >> 16) & 1u);
    return (unsigned short)(b >> 16);
}

// ---------------------------------------------------------------------------
// W fp32 [k][n] -> Wb bf16, k-tiled transpose: Wb[(kt*512 + n)*32 + kk] =
// bf16(W[(kt*32 + kk)*512 + n]).  Each 32 KB slab [kt] is the contiguous
// LDS image for that k-tile (linear global_load_lds).  Verified R2/R4.
// ---------------------------------------------------------------------------
__global__ void convert_w(const float* __restrict__ W, unsigned short* __restrict__ wb) {
    int t  = blockIdx.x * blockDim.x + threadIdx.x;   // 0 .. 262143
    int kk = t & 31;
    int n  = (t >> 5) & 511;
    int kt = t >> 14;
    wb[t] = f2bf(W[(kt * 32 + kk) * 512 + n]);
}

// ---------------------------------------------------------------------------
// y = x @ W + b.  BM=64 rows/block, BN=512 (X read exactly once), BK=32.
// R2 structure (dbuf LDS, barrier per k-tile, B staged via global_load_lds
// from the L2-resident Wb) with two pipeline fixes:
//  1) X loaded TWO tiles ahead; writeA runs right after the barrier on data
//     that has had a full phase to land -> no per-phase X-latency stall and
//     the barrier's vmcnt drain only sees fully-flown loads.
//  2) Epilogue stages acc through LDS and stores Y as contiguous dwordx4
//     (1 KB/instruction full-line bursts) instead of 64 scattered dwords.
// ---------------------------------------------------------------------------
__global__ __launch_bounds__(THREADS, 4) void sparse_dense_gemm(
    const float* __restrict__ X, const unsigned short* __restrict__ Wb,
    const float* __restrict__ bias, float* __restrict__ Y)
{
    extern __shared__ char smem[];
    unsigned short* bufB = (unsigned short*)smem;                    // [2][512*32]
    unsigned short* bufA = (unsigned short*)(smem + 2 * BTILE * 2);  // [2][64*32]

    const int tid  = threadIdx.x;
    const int lane = tid & 63;
    const int wv   = tid >> 6;          // 0..7 -> cols [wv*64, wv*64+64)
    const int r0   = blockIdx.x * BM;
    const int c    = lane & 15;         // frag row/col selector
    const int q    = lane >> 4;         // quad 0..3 -> k-slot q*8..q*8+7

    // A staging map: thread -> (row, float4 k-slot); coalesced 128 B per 8 lanes
    const int arow = tid >> 3;          // 0..63
    const int akd  = tid & 7;           // 0..7
    const float* xsrc = X + (size_t)(r0 + arow) * D_IN + akd * 4;

    auto stageB = [&](int kt, int buf) {
        const unsigned short* src = Wb + (size_t)kt * BTILE;
        unsigned short* dst = bufB + buf * BTILE;
        #pragma unroll
        for (int r = 0; r < 4; ++r) {
            int o = (r * 512 + tid) * 8;   // element offset; x2 B = 16 B/thread, linear
            __builtin_amdgcn_global_load_lds(
                (const __attribute__((address_space(1))) u32*)(src + o),
                (__attribute__((address_space(3)))       u32*)(dst + o),
                16, 0, 0);
        }
    };
    auto writeA = [&](float4 v, int buf) {
        u32 lo = (u32)f2bf(v.x) | ((u32)f2bf(v.y) << 16);
        u32 hi = (u32)f2bf(v.z) | ((u32)f2bf(v.w) << 16);
        *(uint2*)(bufA + buf * ATILE + arow * BK + akd * 4) = make_uint2(lo, hi);
    };

    f4v acc[4][4];
    #pragma unroll
    for (int mf = 0; mf < 4; ++mf)
        #pragma unroll
        for (int nf = 0; nf < 4; ++nf)
            acc[mf][nf] = f4v{0.f, 0.f, 0.f, 0.f};

    // bias per thread, hoisted
    float bv[4];
    #pragma unroll
    for (int nf = 0; nf < 4; ++nf) bv[nf] = bias[wv * 64 + nf * 16 + c];

    // ---- prologue: tile 0 staged; X(1) in flight ----
    float4 xR;
    {
        float4 x0 = *(const float4*)(xsrc);          // X tile 0
        xR = *(const float4*)(xsrc + 1 * BK);        // X tile 1 (depth-2)
        writeA(x0, 0);
        stageB(0, 0);
    }

    int p = 0;
    #pragma unroll 2
    for (int kt = 0; kt < NKT; ++kt) {
        // drain: gll(kt) and xR both issued a FULL phase ago -> cheap drain
        __syncthreads();
        if (kt + 1 < NKT) {
            writeA(xR, p ^ 1);                       // A(kt+1): data already landed
            stageB(kt + 1, p ^ 1);                   // B(kt+1): flies over compute
            if (kt + 2 < NKT)
                xR = *(const float4*)(xsrc + (kt + 2) * BK);   // X(kt+2)
        }

        // ---- compute on buffer p ----
        const unsigned short* Ab = bufA + p * ATILE;
        const unsigned short* Bb = bufB + p * BTILE;
        s8v af[4], bfr[4];
        #pragma unroll
        for (int mf = 0; mf < 4; ++mf)
            af[mf] = *(const s8v*)(Ab + (mf * 16 + c) * BK + q * 8);
        #pragma unroll
        for (int nf = 0; nf < 4; ++nf)
            bfr[nf] = *(const s8v*)(Bb + (wv * 64 + nf * 16 + c) * BK + q * 8);
        #pragma unroll
        for (int mf = 0; mf < 4; ++mf)
            #pragma unroll
            for (int nf = 0; nf < 4; ++nf)
                acc[mf][nf] = __builtin_amdgcn_mfma_f32_16x16x32_bf16(
                    af[mf], bfr[nf], acc[mf][nf], 0, 0, 0);

        p ^= 1;
    }

    // ---- epilogue: stage acc through LDS, store Y as 1 KB contiguous bursts ----
    // acc layout: row_local = mf*16 + q*4 + i, col = wv*64 + nf*16 + c (verified).
    float* ldsY = (float*)smem;                      // reuse 64 KB B region
    #pragma unroll
    for (int pass = 0; pass < 2; ++pass) {           // mf {0,1} then {2,3}
        __syncthreads();                             // LDS region free / prior reads done
        #pragma unroll
        for (int mf2 = 0; mf2 < 2; ++mf2) {
            const int mf = pass * 2 + mf2;
            #pragma unroll
            for (int nf = 0; nf < 4; ++nf) {
                #pragma unroll
                for (int i = 0; i < 4; ++i) {
                    int row = mf2 * 16 + q * 4 + i;          // 0..31 within pass
                    int col = wv * 64 + nf * 16 + c;
                    ldsY[row * 512 + col] = acc[mf][nf][i] + bv[nf];
                }
            }
        }
        __syncthreads();
        // linear read-back: 8 x float4/thread; each store instr = 1 KB contiguous
        const float4* src = (const float4*)ldsY;
        float4* Yv = (float4*)(Y + (size_t)(r0 + 32 * pass) * D_OUT);
        #pragma unroll
        for (int j = 0; j < 8; ++j) {
            float4 v = src[j * 512 + tid];
            Yv[j * 512 + tid] = v;
        }
    }
}

extern "C" void kernel_launch(void* const* d_in, const int* in_sizes, int n_in,
                              void* d_out, int out_size, void* d_ws, size_t ws_size,
                              hipStream_t stream) {
    const float* X    = (const float*)d_in[0];
    const float* W    = (const float*)d_in[1];
    const float* bias = (const float*)d_in[2];
    float* Y          = (float*)d_out;
    unsigned short* wsb = (unsigned short*)d_ws;   // 512 KB bf16 k-tiled W^T copy

    (void)hipFuncSetAttribute((const void*)sparse_dense_gemm,
                              hipFuncAttributeMaxDynamicSharedMemorySize, LDS_BYTES);

    convert_w<<<1024, 256, 0, stream>>>(W, wsb);
    sparse_dense_gemm<<<N_ROWS / BM, THREADS, LDS_BYTES, stream>>>(X, wsb, bias, Y);
}